// Round 1
// baseline (1225.736 us; speedup 1.0000x reference)
//
#include <hip/hip_runtime.h>

// GCN forward: 3x GCNConv (128->64->64->2) + linear head (2->16).
// N=100000 nodes, E=1600000 edges (+N self-loops handled analytically).

#define NF 128
#define NH 64

// Detect whether edge_index arrived as int64 (odd int32 words all zero) or int32.
__global__ void k_detect_fmt(const int* __restrict__ ei, int* __restrict__ flag) {
    if (threadIdx.x == 0 && blockIdx.x == 0) {
        int f = 1;
        #pragma unroll
        for (int i = 1; i < 32; i += 2) if (ei[i] != 0) f = 0;
        *flag = f;   // 1 => int64 layout (stride 2 in int32 words), 0 => int32
    }
}

__global__ void k_deg_init(float* __restrict__ deg, int n) {
    int i = blockIdx.x * 256 + threadIdx.x;
    if (i < n) deg[i] = 1.0f;   // self-loop contributes 1
}

__global__ void k_deg_accum(const int* __restrict__ ei, const int* __restrict__ fmt,
                            float* __restrict__ deg, int E) {
    int e = blockIdx.x * 256 + threadIdx.x;
    if (e >= E) return;
    int sh = *fmt;
    int d = ei[((long long)(E + e)) << sh];
    atomicAdd(&deg[d], 1.0f);
}

__global__ void k_dis(float* __restrict__ deg, int n) {
    int i = blockIdx.x * 256 + threadIdx.x;
    if (i < n) deg[i] = 1.0f / sqrtf(deg[i]);   // deg >= 1 always
}

// t0 = x @ W0 ; agg = t0*dis^2 + b0  (self-loop + bias init)
__global__ void __launch_bounds__(256) k_gemm0(
        const float* __restrict__ x, const float* __restrict__ W0,
        const float* __restrict__ b0, const float* __restrict__ dis,
        float* __restrict__ h, float* __restrict__ agg, int n) {
    __shared__ float Ws[NF * NH];
    __shared__ float xs[4 * NF];
    __shared__ float bs[NH];
    for (int i = threadIdx.x; i < NF * NH; i += 256) Ws[i] = W0[i];
    if (threadIdx.x < NH) bs[threadIdx.x] = b0[threadIdx.x];
    long long base = (long long)blockIdx.x * (4 * NF);
    long long lim = (long long)n * NF;
    long long i0 = base + threadIdx.x, i1 = base + threadIdx.x + 256;
    xs[threadIdx.x]       = (i0 < lim) ? x[i0] : 0.0f;
    xs[threadIdx.x + 256] = (i1 < lim) ? x[i1] : 0.0f;
    __syncthreads();
    int rl = threadIdx.x >> 6, c = threadIdx.x & 63;
    int row = blockIdx.x * 4 + rl;
    if (row >= n) return;
    float acc = 0.0f;
    #pragma unroll 8
    for (int k = 0; k < NF; ++k) acc += xs[rl * NF + k] * Ws[k * NH + c];
    float di = dis[row];
    h[(long long)row * NH + c] = acc;
    agg[(long long)row * NH + c] = acc * di * di + bs[c];
}

// t1 = z0 @ W1 ; agg(in-place over z0) = t1*dis^2 + b1. Safe: z0 rows staged in LDS.
__global__ void __launch_bounds__(256) k_gemm1(
        const float* __restrict__ z0, const float* __restrict__ W1,
        const float* __restrict__ b1, const float* __restrict__ dis,
        float* __restrict__ h, float* __restrict__ agg, int n) {
    __shared__ float Ws[NH * NH];
    __shared__ float xs[4 * NH];
    __shared__ float bs[NH];
    for (int i = threadIdx.x; i < NH * NH; i += 256) Ws[i] = W1[i];
    if (threadIdx.x < NH) bs[threadIdx.x] = b1[threadIdx.x];
    long long idx = (long long)blockIdx.x * 256 + threadIdx.x;
    xs[threadIdx.x] = (idx < (long long)n * NH) ? z0[idx] : 0.0f;
    __syncthreads();
    int rl = threadIdx.x >> 6, c = threadIdx.x & 63;
    int row = blockIdx.x * 4 + rl;
    if (row >= n) return;
    float acc = 0.0f;
    #pragma unroll 8
    for (int k = 0; k < NH; ++k) acc += xs[rl * NH + k] * Ws[k * NH + c];
    float di = dis[row];
    h[(long long)row * NH + c] = acc;
    agg[(long long)row * NH + c] = acc * di * di + bs[c];
}

// agg[dst][c] += h[src][c] * dis[src]*dis[dst]   (one wave per edge, c = lane)
__global__ void __launch_bounds__(256) k_edge_agg(
        const int* __restrict__ ei, const int* __restrict__ fmt,
        const float* __restrict__ dis, const float* __restrict__ h,
        float* __restrict__ agg, int E) {
    long long gid = (long long)blockIdx.x * 256 + threadIdx.x;
    int e = (int)(gid >> 6);
    int c = (int)(gid & 63);
    if (e >= E) return;
    int sh = *fmt;
    int s = ei[((long long)e) << sh];
    int d = ei[((long long)(E + e)) << sh];
    float norm = dis[s] * dis[d];
    float v = h[(long long)s * NH + c] * norm;
    atomicAdd(&agg[(long long)d * NH + c], v);
}

// h1 = tanh(z1); t2 = h1 @ W2 (64x2); agg2 = t2*dis^2 + b2
__global__ void __launch_bounds__(256) k_gemm2(
        const float* __restrict__ z1, const float* __restrict__ W2,
        const float* __restrict__ b2, const float* __restrict__ dis,
        float2* __restrict__ t2, float2* __restrict__ agg2, int n) {
    __shared__ float Ws[NH * 2];
    if (threadIdx.x < NH * 2) Ws[threadIdx.x] = W2[threadIdx.x];
    __syncthreads();
    int i = blockIdx.x * 256 + threadIdx.x;
    if (i >= n) return;
    const float4* zr = (const float4*)(z1 + (long long)i * NH);
    float a0 = 0.0f, a1 = 0.0f;
    #pragma unroll
    for (int k4 = 0; k4 < NH / 4; ++k4) {
        float4 z = zr[k4];
        float t;
        t = tanhf(z.x); a0 += t * Ws[(k4*4+0)*2]; a1 += t * Ws[(k4*4+0)*2+1];
        t = tanhf(z.y); a0 += t * Ws[(k4*4+1)*2]; a1 += t * Ws[(k4*4+1)*2+1];
        t = tanhf(z.z); a0 += t * Ws[(k4*4+2)*2]; a1 += t * Ws[(k4*4+2)*2+1];
        t = tanhf(z.w); a0 += t * Ws[(k4*4+3)*2]; a1 += t * Ws[(k4*4+3)*2+1];
    }
    float di = dis[i], d2 = di * di;
    t2[i] = make_float2(a0, a1);
    agg2[i] = make_float2(a0 * d2 + b2[0], a1 * d2 + b2[1]);
}

// agg2[dst] += t2[src] * norm   (one thread per edge, 2 floats)
__global__ void __launch_bounds__(256) k_edge_agg2(
        const int* __restrict__ ei, const int* __restrict__ fmt,
        const float* __restrict__ dis, const float2* __restrict__ t2,
        float* __restrict__ agg2, int E) {
    int e = blockIdx.x * 256 + threadIdx.x;
    if (e >= E) return;
    int sh = *fmt;
    int s = ei[((long long)e) << sh];
    int d = ei[((long long)(E + e)) << sh];
    float norm = dis[s] * dis[d];
    float2 v = t2[s];
    atomicAdd(&agg2[(long long)d * 2 + 0], v.x * norm);
    atomicAdd(&agg2[(long long)d * 2 + 1], v.y * norm);
}

// emb = tanh(agg2); out = emb @ Wc + bc   (one thread per (node, class))
__global__ void __launch_bounds__(256) k_final(
        const float2* __restrict__ agg2, const float* __restrict__ Wc,
        const float* __restrict__ bc, float* __restrict__ out,
        float* __restrict__ emb, int n) {
    long long gid = (long long)blockIdx.x * 256 + threadIdx.x;
    int i = (int)(gid >> 4);
    int c = (int)(gid & 15);
    if (i >= n) return;
    float2 z = agg2[i];
    float e0 = tanhf(z.x), e1 = tanhf(z.y);
    out[(long long)i * 16 + c] = e0 * Wc[c] + e1 * Wc[16 + c] + bc[c];
    if (c == 0) emb[(long long)i * 2 + 0] = e0;
    if (c == 1) emb[(long long)i * 2 + 1] = e1;
}

extern "C" void kernel_launch(void* const* d_in, const int* in_sizes, int n_in,
                              void* d_out, int out_size, void* d_ws, size_t ws_size,
                              hipStream_t stream) {
    const float* x  = (const float*)d_in[0];
    const int*   ei = (const int*)  d_in[1];
    const float* W0 = (const float*)d_in[2];
    const float* b0 = (const float*)d_in[3];
    const float* W1 = (const float*)d_in[4];
    const float* b1 = (const float*)d_in[5];
    const float* W2 = (const float*)d_in[6];
    const float* b2 = (const float*)d_in[7];
    const float* Wc = (const float*)d_in[8];
    const float* bc = (const float*)d_in[9];

    int N = in_sizes[0] / NF;
    int E = in_sizes[1] / 2;

    float* out = (float*)d_out;                    // [N,16]
    float* emb = out + (long long)N * 16;          // [N,2]

    // workspace layout (fp32): hbuf[N*64] | aggbuf[N*64] | deg/dis[N] | t2[N*2] | agg2[N*2] | fmt
    float* hbuf   = (float*)d_ws;
    float* aggbuf = hbuf + (long long)N * NH;
    float* deg    = aggbuf + (long long)N * NH;
    float* t2     = deg + N;
    float* agg2   = t2 + (long long)N * 2;
    int*   fmt    = (int*)(agg2 + (long long)N * 2);

    int nb_n   = (N + 255) / 256;
    int nb_e   = (E + 255) / 256;
    int nb_r4  = (N + 3) / 4;
    int nb_e64 = (int)(((long long)E * 64 + 255) / 256);
    int nb_n16 = (int)(((long long)N * 16 + 255) / 256);

    k_detect_fmt<<<1, 64, 0, stream>>>(ei, fmt);
    k_deg_init  <<<nb_n, 256, 0, stream>>>(deg, N);
    k_deg_accum <<<nb_e, 256, 0, stream>>>(ei, fmt, deg, E);
    k_dis       <<<nb_n, 256, 0, stream>>>(deg, N);

    // layer 0 (no activation)
    k_gemm0     <<<nb_r4, 256, 0, stream>>>(x, W0, b0, deg, hbuf, aggbuf, N);
    k_edge_agg  <<<nb_e64, 256, 0, stream>>>(ei, fmt, deg, hbuf, aggbuf, E);

    // layer 1 (tanh fused into layer-2 transform read)
    k_gemm1     <<<nb_r4, 256, 0, stream>>>(aggbuf, W1, b1, deg, hbuf, aggbuf, N);
    k_edge_agg  <<<nb_e64, 256, 0, stream>>>(ei, fmt, deg, hbuf, aggbuf, E);

    // layer 2 (2-wide) + head
    k_gemm2     <<<nb_n, 256, 0, stream>>>(aggbuf, W2, b2, deg, (float2*)t2, (float2*)agg2, N);
    k_edge_agg2 <<<nb_e, 256, 0, stream>>>(ei, fmt, deg, (const float2*)t2, agg2, E);
    k_final     <<<nb_n16, 256, 0, stream>>>((const float2*)agg2, Wc, bc, out, emb, N);
}

// Round 2
// 557.813 us; speedup vs baseline: 2.1974x; 2.1974x over previous
//
#include <hip/hip_runtime.h>

// GCN forward: 3x GCNConv (128->64->64->2) + linear head (2->16).
// N=100000 nodes, E=1600000 edges (+self-loops handled analytically).
// Strategy: dst-bucket the edges per call (histogram + unordered block-scan +
// scatter), then aggregate via atomic-free segment-sum gathers (one wave/node).

#define NF 128
#define NH 64

// Detect whether edge_index arrived as int64 (odd int32 words all zero) or int32.
__global__ void k_detect_fmt(const int* __restrict__ ei, int* __restrict__ flag) {
    if (threadIdx.x == 0 && blockIdx.x == 0) {
        int f = 1;
        #pragma unroll
        for (int i = 1; i < 32; i += 2) if (ei[i] != 0) f = 0;
        *flag = f;   // 1 => int64 layout (stride 2 in int32 words), 0 => int32
    }
}

__global__ void k_zero(int* __restrict__ cnt, int* __restrict__ gcount, int n) {
    int i = blockIdx.x * 256 + threadIdx.x;
    if (i < n) cnt[i] = 0;
    if (i == 0 && blockIdx.x == 0) *gcount = 0;
}

__global__ void k_cnt(const int* __restrict__ ei, const int* __restrict__ fmt,
                      int* __restrict__ cnt, int E) {
    int e = blockIdx.x * 256 + threadIdx.x;
    if (e >= E) return;
    int sh = *fmt;
    int d = ei[((long long)(E + e)) << sh];
    atomicAdd(&cnt[d], 1);
}

// Unordered exclusive scan: block-local Hillis-Steele + atomic block base.
// Bucket ranges are a valid disjoint partition regardless of block order.
__global__ void __launch_bounds__(256) k_scan(
        const int* __restrict__ cnt, int* __restrict__ start,
        int* __restrict__ cursor, float* __restrict__ dis,
        int* __restrict__ gcount, int n) {
    __shared__ int s[256];
    __shared__ int base_s;
    int i = blockIdx.x * 256 + threadIdx.x;
    int c = (i < n) ? cnt[i] : 0;
    s[threadIdx.x] = c;
    __syncthreads();
    for (int off = 1; off < 256; off <<= 1) {
        int v = s[threadIdx.x];
        int u = (threadIdx.x >= off) ? s[threadIdx.x - off] : 0;
        __syncthreads();
        s[threadIdx.x] = v + u;
        __syncthreads();
    }
    if (threadIdx.x == 255) base_s = atomicAdd(gcount, s[255]);
    __syncthreads();
    if (i < n) {
        int st = base_s + s[threadIdx.x] - c;
        start[i] = st;
        cursor[i] = st;
        dis[i] = rsqrtf(1.0f + (float)c);   // degree includes self-loop
    }
}

__global__ void k_scatter(const int* __restrict__ ei, const int* __restrict__ fmt,
                          int* __restrict__ cursor, int* __restrict__ esrc, int E) {
    int e = blockIdx.x * 256 + threadIdx.x;
    if (e >= E) return;
    int sh = *fmt;
    int s = ei[((long long)e) << sh];
    int d = ei[((long long)(E + e)) << sh];
    int pos = atomicAdd(&cursor[d], 1);
    esrc[pos] = s;
}

// T[n,NH] = X[n,K] @ W[K,NH].  16 rows/block, 4 rows/thread (W value reused 4x).
template<int K>
__global__ void __launch_bounds__(256) k_gemm(
        const float* __restrict__ X, const float* __restrict__ W,
        float* __restrict__ T, int n) {
    __shared__ float Ws[K * NH];
    __shared__ float xs[16 * K];
    for (int i = threadIdx.x; i < K * NH; i += 256) Ws[i] = W[i];
    long long base = (long long)blockIdx.x * (16 * K);
    long long lim = (long long)n * K;
    for (int i = threadIdx.x; i < 16 * K; i += 256) {
        long long g = base + i;
        xs[i] = (g < lim) ? X[g] : 0.0f;
    }
    __syncthreads();
    int c = threadIdx.x & 63, rg = threadIdx.x >> 6;
    const float* xr = &xs[rg * 4 * K];
    float a0 = 0.f, a1 = 0.f, a2 = 0.f, a3 = 0.f;
    #pragma unroll 4
    for (int k = 0; k < K; ++k) {
        float w = Ws[k * NH + c];
        a0 += xr[0 * K + k] * w;
        a1 += xr[1 * K + k] * w;
        a2 += xr[2 * K + k] * w;
        a3 += xr[3 * K + k] * w;
    }
    int row = blockIdx.x * 16 + rg * 4;
    if (row + 0 < n) T[(long long)(row + 0) * NH + c] = a0;
    if (row + 1 < n) T[(long long)(row + 1) * NH + c] = a1;
    if (row + 2 < n) T[(long long)(row + 2) * NH + c] = a2;
    if (row + 3 < n) T[(long long)(row + 3) * NH + c] = a3;
}

// O[i] = T[i]*di^2 + b + di * sum_{s in bucket(i)} dis[s]*T[s]   (wave per node)
__global__ void __launch_bounds__(256) k_seg(
        const float* __restrict__ T, const int* __restrict__ esrc,
        const int* __restrict__ start, const int* __restrict__ cnt,
        const float* __restrict__ dis, const float* __restrict__ b,
        float* __restrict__ O, int n) {
    int lane = threadIdx.x & 63;
    int node = blockIdx.x * 4 + (threadIdx.x >> 6);
    if (node >= n) return;
    float di = dis[node];
    int g = cnt[node], st = start[node];
    float acc = 0.0f;
    for (int base = 0; base < g; base += 64) {
        int m = g - base; if (m > 64) m = 64;
        int sIdx = 0; float nv = 0.0f;
        if (lane < m) { sIdx = esrc[st + base + lane]; nv = dis[sIdx]; }
        int j = 0;
        for (; j + 3 < m; j += 4) {
            int s0 = __shfl(sIdx, j, 64),   s1 = __shfl(sIdx, j+1, 64);
            int s2 = __shfl(sIdx, j+2, 64), s3 = __shfl(sIdx, j+3, 64);
            float n0 = __shfl(nv, j, 64),   n1 = __shfl(nv, j+1, 64);
            float n2 = __shfl(nv, j+2, 64), n3 = __shfl(nv, j+3, 64);
            float v0 = T[(long long)s0 * NH + lane];
            float v1 = T[(long long)s1 * NH + lane];
            float v2 = T[(long long)s2 * NH + lane];
            float v3 = T[(long long)s3 * NH + lane];
            acc += v0 * n0; acc += v1 * n1; acc += v2 * n2; acc += v3 * n3;
        }
        for (; j < m; ++j) {
            int ss = __shfl(sIdx, j, 64);
            float nn = __shfl(nv, j, 64);
            acc += T[(long long)ss * NH + lane] * nn;
        }
    }
    float self = T[(long long)node * NH + lane];
    O[(long long)node * NH + lane] = self * di * di + b[lane] + di * acc;
}

// t2 = tanh(z1) @ W2  (64x2)
__global__ void __launch_bounds__(256) k_gemm2(
        const float* __restrict__ z1, const float* __restrict__ W2,
        float2* __restrict__ t2, int n) {
    __shared__ float Ws[NH * 2];
    if (threadIdx.x < NH * 2) Ws[threadIdx.x] = W2[threadIdx.x];
    __syncthreads();
    int i = blockIdx.x * 256 + threadIdx.x;
    if (i >= n) return;
    const float4* zr = (const float4*)(z1 + (long long)i * NH);
    float a0 = 0.0f, a1 = 0.0f;
    #pragma unroll
    for (int k4 = 0; k4 < NH / 4; ++k4) {
        float4 z = zr[k4];
        float t;
        t = tanhf(z.x); a0 += t * Ws[(k4*4+0)*2]; a1 += t * Ws[(k4*4+0)*2+1];
        t = tanhf(z.y); a0 += t * Ws[(k4*4+1)*2]; a1 += t * Ws[(k4*4+1)*2+1];
        t = tanhf(z.z); a0 += t * Ws[(k4*4+2)*2]; a1 += t * Ws[(k4*4+2)*2+1];
        t = tanhf(z.w); a0 += t * Ws[(k4*4+3)*2]; a1 += t * Ws[(k4*4+3)*2+1];
    }
    t2[i] = make_float2(a0, a1);
}

// agg2[i] = t2[i]*di^2 + b2 + di * sum dis[s]*t2[s]   (thread per node)
__global__ void __launch_bounds__(256) k_seg2(
        const float2* __restrict__ T2, const int* __restrict__ esrc,
        const int* __restrict__ start, const int* __restrict__ cnt,
        const float* __restrict__ dis, const float* __restrict__ b2,
        float2* __restrict__ O, int n) {
    int i = blockIdx.x * 256 + threadIdx.x;
    if (i >= n) return;
    float di = dis[i];
    int g = cnt[i], st = start[i];
    float a0 = 0.0f, a1 = 0.0f;
    for (int j = 0; j < g; ++j) {
        int s = esrc[st + j];
        float nn = dis[s];
        float2 v = T2[s];
        a0 += v.x * nn; a1 += v.y * nn;
    }
    float2 self = T2[i];
    O[i] = make_float2(self.x * di * di + b2[0] + di * a0,
                       self.y * di * di + b2[1] + di * a1);
}

// emb = tanh(agg2) (in place: agg2 aliases emb region); out = emb @ Wc + bc.
// The 16 class-threads of node i live in one wave -> loads precede stores.
__global__ void __launch_bounds__(256) k_final(
        const float2* __restrict__ agg2, const float* __restrict__ Wc,
        const float* __restrict__ bc, float* __restrict__ out,
        float* __restrict__ emb, int n) {
    long long gid = (long long)blockIdx.x * 256 + threadIdx.x;
    int i = (int)(gid >> 4);
    int c = (int)(gid & 15);
    if (i >= n) return;
    float2 z = agg2[i];
    float e0 = tanhf(z.x), e1 = tanhf(z.y);
    out[(long long)i * 16 + c] = e0 * Wc[c] + e1 * Wc[16 + c] + bc[c];
    if (c == 0) emb[(long long)i * 2 + 0] = e0;
    if (c == 1) emb[(long long)i * 2 + 1] = e1;
}

extern "C" void kernel_launch(void* const* d_in, const int* in_sizes, int n_in,
                              void* d_out, int out_size, void* d_ws, size_t ws_size,
                              hipStream_t stream) {
    const float* x  = (const float*)d_in[0];
    const int*   ei = (const int*)  d_in[1];
    const float* W0 = (const float*)d_in[2];
    const float* b0 = (const float*)d_in[3];
    const float* W1 = (const float*)d_in[4];
    const float* b1 = (const float*)d_in[5];
    const float* W2 = (const float*)d_in[6];
    const float* b2 = (const float*)d_in[7];
    const float* Wc = (const float*)d_in[8];
    const float* bc = (const float*)d_in[9];

    int N = in_sizes[0] / NF;
    int E = in_sizes[1] / 2;

    float* out = (float*)d_out;                    // [N,16]
    float* emb = out + (long long)N * 16;          // [N,2]
    // t2 scratch lives in the out region (overwritten by k_final afterwards);
    // agg2 lives in the emb region (tanh'd in place by k_final).
    float2* t2   = (float2*)out;
    float2* agg2 = (float2*)emb;

    // workspace: A[N*64] | B[N*64] | dis[N] | cnt[N] | start[N] | cursor[N] | esrc[E] | fmt | gcount
    float* A      = (float*)d_ws;
    float* B      = A + (long long)N * NH;
    float* dis    = B + (long long)N * NH;
    int*   cnt    = (int*)(dis + N);
    int*   start  = cnt + N;
    int*   cursor = start + N;
    int*   esrc   = cursor + N;
    int*   fmt    = esrc + E;
    int*   gcount = fmt + 1;

    int nb_n   = (N + 255) / 256;
    int nb_e   = (E + 255) / 256;
    int nb_g   = (N + 15) / 16;
    int nb_s   = (N + 3) / 4;
    int nb_n16 = (int)(((long long)N * 16 + 255) / 256);

    k_detect_fmt<<<1, 64, 0, stream>>>(ei, fmt);

    // per-call bucketing (edge_index restored before every call; same work each call)
    k_zero    <<<nb_n, 256, 0, stream>>>(cnt, gcount, N);
    k_cnt     <<<nb_e, 256, 0, stream>>>(ei, fmt, cnt, E);
    k_scan    <<<nb_n, 256, 0, stream>>>(cnt, start, cursor, dis, gcount, N);
    k_scatter <<<nb_e, 256, 0, stream>>>(ei, fmt, cursor, esrc, E);

    // layer 0 (no activation)
    k_gemm<NF><<<nb_g, 256, 0, stream>>>(x, W0, A, N);
    k_seg     <<<nb_s, 256, 0, stream>>>(A, esrc, start, cnt, dis, b0, B, N);

    // layer 1 (tanh deferred into k_gemm2's read)
    k_gemm<NH><<<nb_g, 256, 0, stream>>>(B, W1, A, N);
    k_seg     <<<nb_s, 256, 0, stream>>>(A, esrc, start, cnt, dis, b1, B, N);

    // layer 2 (2-wide) + head
    k_gemm2   <<<nb_n, 256, 0, stream>>>(B, W2, t2, N);
    k_seg2    <<<nb_n, 256, 0, stream>>>(t2, esrc, start, cnt, dis, b2, agg2, N);
    k_final   <<<nb_n16, 256, 0, stream>>>(agg2, Wc, bc, out, emb, N);
}

// Round 3
// 454.644 us; speedup vs baseline: 2.6960x; 1.2269x over previous
//
#include <hip/hip_runtime.h>

// GCN forward: 3x GCNConv (128->64->64->2) + linear head (2->16).
// N=100000 nodes, E=1600000 edges (+self-loops handled analytically).
// Strategy: dst-bucket edges per call (histogram-with-rank + unordered block
// scan + atomic-free scatter), then atomic-free segment-sum gathers.
// dis[] is pre-folded into the transform outputs: T'[v] = dis[v]*t[v], so
// O[i] = dis[i]*(T'[i] + sum_{s in bucket(i)} T'[s]) + b.

#define NF 128
#define NH 64

// Detect int64 vs int32 edge_index layout + zero the histogram.
__global__ void k_init(const int* __restrict__ ei, int* __restrict__ flag,
                       int* __restrict__ cnt, int* __restrict__ gcount, int n) {
    int i = blockIdx.x * 256 + threadIdx.x;
    if (i < n) cnt[i] = 0;
    if (blockIdx.x == 0 && threadIdx.x == 0) {
        int f = 1;
        #pragma unroll
        for (int k = 1; k < 32; k += 2) if (ei[k] != 0) f = 0;
        *flag = f;   // 1 => int64 (stride 2 in int32 words), 0 => int32
        *gcount = 0;
    }
}

// Histogram dst; the atomic's return value IS the edge's within-bucket rank.
__global__ void k_cnt(const int* __restrict__ ei, const int* __restrict__ fmt,
                      int* __restrict__ cnt, int* __restrict__ rank, int E) {
    int e = blockIdx.x * 256 + threadIdx.x;
    if (e >= E) return;
    int sh = *fmt;
    int d = ei[((long long)(E + e)) << sh];
    rank[e] = atomicAdd(&cnt[d], 1);
}

// Unordered exclusive scan: block-local Hillis-Steele + atomic block base.
// Bucket ranges are a valid disjoint partition regardless of block order.
__global__ void __launch_bounds__(256) k_scan(
        const int* __restrict__ cnt, int* __restrict__ start,
        float* __restrict__ dis, int* __restrict__ gcount, int n) {
    __shared__ int s[256];
    __shared__ int base_s;
    int i = blockIdx.x * 256 + threadIdx.x;
    int c = (i < n) ? cnt[i] : 0;
    s[threadIdx.x] = c;
    __syncthreads();
    for (int off = 1; off < 256; off <<= 1) {
        int v = s[threadIdx.x];
        int u = (threadIdx.x >= off) ? s[threadIdx.x - off] : 0;
        __syncthreads();
        s[threadIdx.x] = v + u;
        __syncthreads();
    }
    if (threadIdx.x == 255) base_s = atomicAdd(gcount, s[255]);
    __syncthreads();
    if (i < n) {
        start[i] = base_s + s[threadIdx.x] - c;
        dis[i] = rsqrtf(1.0f + (float)c);   // degree includes self-loop
    }
}

// Atomic-free scatter: position is start[dst] + precomputed rank.
__global__ void k_scatter(const int* __restrict__ ei, const int* __restrict__ fmt,
                          const int* __restrict__ start, const int* __restrict__ rank,
                          int* __restrict__ esrc, int E) {
    int e = blockIdx.x * 256 + threadIdx.x;
    if (e >= E) return;
    int sh = *fmt;
    int s = ei[((long long)e) << sh];
    int d = ei[((long long)(E + e)) << sh];
    esrc[start[d] + rank[e]] = s;
}

// T[n,NH] = dis[n] * (X[n,K] @ W[K,NH]).  16 rows/block, 4 rows/thread.
template<int K>
__global__ void __launch_bounds__(256) k_gemm(
        const float* __restrict__ X, const float* __restrict__ W,
        const float* __restrict__ dis, float* __restrict__ T, int n) {
    __shared__ float Ws[K * NH];
    __shared__ float xs[16 * K];
    for (int i = threadIdx.x; i < K * NH; i += 256) Ws[i] = W[i];
    long long base = (long long)blockIdx.x * (16 * K);
    long long lim = (long long)n * K;
    for (int i = threadIdx.x; i < 16 * K; i += 256) {
        long long g = base + i;
        xs[i] = (g < lim) ? X[g] : 0.0f;
    }
    __syncthreads();
    int c = threadIdx.x & 63, rg = threadIdx.x >> 6;
    const float* xr = &xs[rg * 4 * K];
    float a0 = 0.f, a1 = 0.f, a2 = 0.f, a3 = 0.f;
    #pragma unroll 4
    for (int k = 0; k < K; ++k) {
        float w = Ws[k * NH + c];
        a0 += xr[0 * K + k] * w;
        a1 += xr[1 * K + k] * w;
        a2 += xr[2 * K + k] * w;
        a3 += xr[3 * K + k] * w;
    }
    int row = blockIdx.x * 16 + rg * 4;
    if (row + 0 < n) T[(long long)(row + 0) * NH + c] = a0 * dis[row + 0];
    if (row + 1 < n) T[(long long)(row + 1) * NH + c] = a1 * dis[row + 1];
    if (row + 2 < n) T[(long long)(row + 2) * NH + c] = a2 * dis[row + 2];
    if (row + 3 < n) T[(long long)(row + 3) * NH + c] = a3 * dis[row + 3];
}

// O[i] = dis[i]*(T[i] + sum_{s in bucket(i)} T[s]) + b   (wave per node)
__global__ void __launch_bounds__(256) k_seg(
        const float* __restrict__ T, const int* __restrict__ esrc,
        const int* __restrict__ start, const int* __restrict__ cnt,
        const float* __restrict__ dis, const float* __restrict__ b,
        float* __restrict__ O, int n) {
    int lane = threadIdx.x & 63;
    int node = blockIdx.x * 4 + (threadIdx.x >> 6);
    if (node >= n) return;
    float di = dis[node];
    int g = cnt[node], st = start[node];
    float acc = T[(long long)node * NH + lane];   // self-loop term (pre-scaled)
    for (int base = 0; base < g; base += 64) {
        int m = g - base; if (m > 64) m = 64;
        int sIdx = (lane < m) ? esrc[st + base + lane] : 0;
        int j = 0;
        for (; j + 3 < m; j += 4) {
            int s0 = __shfl(sIdx, j, 64),   s1 = __shfl(sIdx, j+1, 64);
            int s2 = __shfl(sIdx, j+2, 64), s3 = __shfl(sIdx, j+3, 64);
            float v0 = T[(long long)s0 * NH + lane];
            float v1 = T[(long long)s1 * NH + lane];
            float v2 = T[(long long)s2 * NH + lane];
            float v3 = T[(long long)s3 * NH + lane];
            acc += v0; acc += v1; acc += v2; acc += v3;
        }
        for (; j < m; ++j)
            acc += T[(long long)__shfl(sIdx, j, 64) * NH + lane];
    }
    O[(long long)node * NH + lane] = di * acc + b[lane];
}

// t2'[i] = dis[i] * (tanh(z1[i]) @ W2)  (64x2)
__global__ void __launch_bounds__(256) k_gemm2(
        const float* __restrict__ z1, const float* __restrict__ W2,
        const float* __restrict__ dis, float2* __restrict__ t2, int n) {
    __shared__ float Ws[NH * 2];
    if (threadIdx.x < NH * 2) Ws[threadIdx.x] = W2[threadIdx.x];
    __syncthreads();
    int i = blockIdx.x * 256 + threadIdx.x;
    if (i >= n) return;
    const float4* zr = (const float4*)(z1 + (long long)i * NH);
    float a0 = 0.0f, a1 = 0.0f;
    #pragma unroll
    for (int k4 = 0; k4 < NH / 4; ++k4) {
        float4 z = zr[k4];
        float t;
        t = tanhf(z.x); a0 += t * Ws[(k4*4+0)*2]; a1 += t * Ws[(k4*4+0)*2+1];
        t = tanhf(z.y); a0 += t * Ws[(k4*4+1)*2]; a1 += t * Ws[(k4*4+1)*2+1];
        t = tanhf(z.z); a0 += t * Ws[(k4*4+2)*2]; a1 += t * Ws[(k4*4+2)*2+1];
        t = tanhf(z.w); a0 += t * Ws[(k4*4+3)*2]; a1 += t * Ws[(k4*4+3)*2+1];
    }
    float di = dis[i];
    t2[i] = make_float2(a0 * di, a1 * di);
}

// agg2[i] = dis[i]*(t2[i] + sum t2[s]) + b2   (thread per node)
__global__ void __launch_bounds__(256) k_seg2(
        const float2* __restrict__ T2, const int* __restrict__ esrc,
        const int* __restrict__ start, const int* __restrict__ cnt,
        const float* __restrict__ dis, const float* __restrict__ b2,
        float2* __restrict__ O, int n) {
    int i = blockIdx.x * 256 + threadIdx.x;
    if (i >= n) return;
    float di = dis[i];
    int g = cnt[i], st = start[i];
    float2 self = T2[i];
    float a0 = self.x, a1 = self.y;
    for (int j = 0; j < g; ++j) {
        float2 v = T2[esrc[st + j]];
        a0 += v.x; a1 += v.y;
    }
    O[i] = make_float2(a0 * di + b2[0], a1 * di + b2[1]);
}

// emb = tanh(agg2) (agg2 aliases emb region); out = emb @ Wc + bc.
__global__ void __launch_bounds__(256) k_final(
        const float2* __restrict__ agg2, const float* __restrict__ Wc,
        const float* __restrict__ bc, float* __restrict__ out,
        float* __restrict__ emb, int n) {
    long long gid = (long long)blockIdx.x * 256 + threadIdx.x;
    int i = (int)(gid >> 4);
    int c = (int)(gid & 15);
    if (i >= n) return;
    float2 z = agg2[i];
    float e0 = tanhf(z.x), e1 = tanhf(z.y);
    out[(long long)i * 16 + c] = e0 * Wc[c] + e1 * Wc[16 + c] + bc[c];
    if (c == 0) emb[(long long)i * 2 + 0] = e0;
    if (c == 1) emb[(long long)i * 2 + 1] = e1;
}

extern "C" void kernel_launch(void* const* d_in, const int* in_sizes, int n_in,
                              void* d_out, int out_size, void* d_ws, size_t ws_size,
                              hipStream_t stream) {
    const float* x  = (const float*)d_in[0];
    const int*   ei = (const int*)  d_in[1];
    const float* W0 = (const float*)d_in[2];
    const float* b0 = (const float*)d_in[3];
    const float* W1 = (const float*)d_in[4];
    const float* b1 = (const float*)d_in[5];
    const float* W2 = (const float*)d_in[6];
    const float* b2 = (const float*)d_in[7];
    const float* Wc = (const float*)d_in[8];
    const float* bc = (const float*)d_in[9];

    int N = in_sizes[0] / NF;
    int E = in_sizes[1] / 2;

    float* out = (float*)d_out;                    // [N,16]
    float* emb = out + (long long)N * 16;          // [N,2]
    float2* t2   = (float2*)out;                   // scratch in out region
    float2* agg2 = (float2*)emb;                   // tanh'd in place by k_final

    // workspace: A[N*64] | B[N*64] | dis[N] | cnt[N] | start[N] | esrc[E] | fmt | gcount
    // rank[E] overlays A (A is dead until the GEMMs, which run after k_scatter).
    float* A      = (float*)d_ws;
    float* B      = A + (long long)N * NH;
    float* dis    = B + (long long)N * NH;
    int*   cnt    = (int*)(dis + N);
    int*   start  = cnt + N;
    int*   esrc   = start + N;
    int*   fmt    = esrc + E;
    int*   gcount = fmt + 1;
    int*   rank   = (int*)A;

    int nb_n   = (N + 255) / 256;
    int nb_e   = (E + 255) / 256;
    int nb_g   = (N + 15) / 16;
    int nb_s   = (N + 3) / 4;
    int nb_n16 = (int)(((long long)N * 16 + 255) / 256);

    // per-call bucketing (inputs restored before every call; same work each call)
    k_init    <<<nb_n, 256, 0, stream>>>(ei, fmt, cnt, gcount, N);
    k_cnt     <<<nb_e, 256, 0, stream>>>(ei, fmt, cnt, rank, E);
    k_scan    <<<nb_n, 256, 0, stream>>>(cnt, start, dis, gcount, N);
    k_scatter <<<nb_e, 256, 0, stream>>>(ei, fmt, start, rank, esrc, E);

    // layer 0 (no activation)
    k_gemm<NF><<<nb_g, 256, 0, stream>>>(x, W0, dis, A, N);
    k_seg     <<<nb_s, 256, 0, stream>>>(A, esrc, start, cnt, dis, b0, B, N);

    // layer 1 (tanh deferred into k_gemm2's read)
    k_gemm<NH><<<nb_g, 256, 0, stream>>>(B, W1, dis, A, N);
    k_seg     <<<nb_s, 256, 0, stream>>>(A, esrc, start, cnt, dis, b1, B, N);

    // layer 2 (2-wide) + head
    k_gemm2   <<<nb_n, 256, 0, stream>>>(B, W2, dis, t2, N);
    k_seg2    <<<nb_n, 256, 0, stream>>>(t2, esrc, start, cnt, dis, b2, agg2, N);
    k_final   <<<nb_n16, 256, 0, stream>>>(agg2, Wc, bc, out, emb, N);
}

// Round 4
// 417.104 us; speedup vs baseline: 2.9387x; 1.0900x over previous
//
#include <hip/hip_runtime.h>

// GCN forward: 3x GCNConv (128->64->64->2) + linear head (2->16).
// N=100000 nodes, E=1600000 edges (+self-loops handled analytically).
// Strategy: dst-bucket edges per call (histogram-with-rank + unordered block
// scan + atomic-free scatter), then atomic-free segment-sum gathers.
// dis[] is pre-folded into the transform outputs: T'[v] = dis[v]*t[v], so
// O[i] = dis[i]*(T'[i] + sum_{s in bucket(i)} T'[s]) + b.

#define NF 128
#define NH 64

// Detect int64 vs int32 edge_index layout + zero the histogram.
__global__ void k_init(const int* __restrict__ ei, int* __restrict__ flag,
                       int* __restrict__ cnt, int* __restrict__ gcount, int n) {
    int i = blockIdx.x * 256 + threadIdx.x;
    if (i < n) cnt[i] = 0;
    if (blockIdx.x == 0 && threadIdx.x == 0) {
        int f = 1;
        #pragma unroll
        for (int k = 1; k < 32; k += 2) if (ei[k] != 0) f = 0;
        *flag = f;   // 1 => int64 (stride 2 in int32 words), 0 => int32
        *gcount = 0;
    }
}

// Histogram dst; the atomic's return value IS the edge's within-bucket rank.
__global__ void k_cnt(const int* __restrict__ ei, const int* __restrict__ fmt,
                      int* __restrict__ cnt, int* __restrict__ rank, int E) {
    int e = blockIdx.x * 256 + threadIdx.x;
    if (e >= E) return;
    int sh = *fmt;
    int d = ei[((long long)(E + e)) << sh];
    rank[e] = atomicAdd(&cnt[d], 1);
}

// Unordered exclusive scan: block-local Hillis-Steele + atomic block base.
// Bucket ranges are a valid disjoint partition regardless of block order.
__global__ void __launch_bounds__(256) k_scan(
        const int* __restrict__ cnt, int* __restrict__ start,
        float* __restrict__ dis, int* __restrict__ gcount, int n) {
    __shared__ int s[256];
    __shared__ int base_s;
    int i = blockIdx.x * 256 + threadIdx.x;
    int c = (i < n) ? cnt[i] : 0;
    s[threadIdx.x] = c;
    __syncthreads();
    for (int off = 1; off < 256; off <<= 1) {
        int v = s[threadIdx.x];
        int u = (threadIdx.x >= off) ? s[threadIdx.x - off] : 0;
        __syncthreads();
        s[threadIdx.x] = v + u;
        __syncthreads();
    }
    if (threadIdx.x == 255) base_s = atomicAdd(gcount, s[255]);
    __syncthreads();
    if (i < n) {
        start[i] = base_s + s[threadIdx.x] - c;
        dis[i] = rsqrtf(1.0f + (float)c);   // degree includes self-loop
    }
}

// Atomic-free scatter: position is start[dst] + precomputed rank.
__global__ void k_scatter(const int* __restrict__ ei, const int* __restrict__ fmt,
                          const int* __restrict__ start, const int* __restrict__ rank,
                          int* __restrict__ esrc, int E) {
    int e = blockIdx.x * 256 + threadIdx.x;
    if (e >= E) return;
    int sh = *fmt;
    int s = ei[((long long)e) << sh];
    int d = ei[((long long)(E + e)) << sh];
    esrc[start[d] + rank[e]] = s;
}

// T[n,NH] = dis[n] * (X[n,K] @ W[K,NH]).
// 64 rows/block, 256 threads, 4 rows x 4 cols per thread (16 acc).
// xs padded to K+4 floats/row: keeps 16B alignment for b128 AND spreads the
// 4 row-broadcast reads across distinct banks ((4r+k)%32).
template<int K>
__global__ void __launch_bounds__(256) k_gemm(
        const float* __restrict__ X, const float* __restrict__ W,
        const float* __restrict__ dis, float* __restrict__ T, int n) {
    constexpr int KP = K + 4;
    __shared__ float xs[64 * KP];
    __shared__ float Ws[K * NH];
    for (int i = threadIdx.x; i < K * NH / 4; i += 256)
        ((float4*)Ws)[i] = ((const float4*)W)[i];
    long long rowbase = (long long)blockIdx.x * 64;
    const float4* X4 = (const float4*)(X + rowbase * K);
    long long lim4 = ((long long)n * K - rowbase * K) >> 2;  // remaining float4s
    for (int i = threadIdx.x; i < 16 * K; i += 256) {
        float4 v = (i < lim4) ? X4[i] : make_float4(0.f, 0.f, 0.f, 0.f);
        int r = i / (K / 4), kk = (i % (K / 4)) * 4;
        *(float4*)&xs[r * KP + kk] = v;
    }
    __syncthreads();
    int c0 = (threadIdx.x & 15) * 4;
    int r0 = (threadIdx.x >> 4) * 4;
    const float* x0 = &xs[(r0 + 0) * KP];
    const float* x1 = &xs[(r0 + 1) * KP];
    const float* x2 = &xs[(r0 + 2) * KP];
    const float* x3 = &xs[(r0 + 3) * KP];
    float4 a0{0,0,0,0}, a1{0,0,0,0}, a2{0,0,0,0}, a3{0,0,0,0};
    #pragma unroll 4
    for (int k = 0; k < K; ++k) {
        float4 w = *(const float4*)&Ws[k * NH + c0];
        float v0 = x0[k], v1 = x1[k], v2 = x2[k], v3 = x3[k];
        a0.x += v0 * w.x; a0.y += v0 * w.y; a0.z += v0 * w.z; a0.w += v0 * w.w;
        a1.x += v1 * w.x; a1.y += v1 * w.y; a1.z += v1 * w.z; a1.w += v1 * w.w;
        a2.x += v2 * w.x; a2.y += v2 * w.y; a2.z += v2 * w.z; a2.w += v2 * w.w;
        a3.x += v3 * w.x; a3.y += v3 * w.y; a3.z += v3 * w.z; a3.w += v3 * w.w;
    }
    int row = (int)rowbase + r0;
    if (row + 0 < n) { float d = dis[row + 0];
        a0.x *= d; a0.y *= d; a0.z *= d; a0.w *= d;
        *(float4*)&T[(long long)(row + 0) * NH + c0] = a0; }
    if (row + 1 < n) { float d = dis[row + 1];
        a1.x *= d; a1.y *= d; a1.z *= d; a1.w *= d;
        *(float4*)&T[(long long)(row + 1) * NH + c0] = a1; }
    if (row + 2 < n) { float d = dis[row + 2];
        a2.x *= d; a2.y *= d; a2.z *= d; a2.w *= d;
        *(float4*)&T[(long long)(row + 2) * NH + c0] = a2; }
    if (row + 3 < n) { float d = dis[row + 3];
        a3.x *= d; a3.y *= d; a3.z *= d; a3.w *= d;
        *(float4*)&T[(long long)(row + 3) * NH + c0] = a3; }
}

// O[i] = dis[i]*(T[i] + sum_{s in bucket(i)} T[s]) + b   (wave per node)
__global__ void __launch_bounds__(256) k_seg(
        const float* __restrict__ T, const int* __restrict__ esrc,
        const int* __restrict__ start, const int* __restrict__ cnt,
        const float* __restrict__ dis, const float* __restrict__ b,
        float* __restrict__ O, int n) {
    int lane = threadIdx.x & 63;
    int node = blockIdx.x * 4 + (threadIdx.x >> 6);
    if (node >= n) return;
    float di = dis[node];
    int g = cnt[node], st = start[node];
    float acc = T[(long long)node * NH + lane];   // self-loop term (pre-scaled)
    for (int base = 0; base < g; base += 64) {
        int m = g - base; if (m > 64) m = 64;
        int sIdx = (lane < m) ? esrc[st + base + lane] : 0;
        int j = 0;
        for (; j + 3 < m; j += 4) {
            int s0 = __shfl(sIdx, j, 64),   s1 = __shfl(sIdx, j+1, 64);
            int s2 = __shfl(sIdx, j+2, 64), s3 = __shfl(sIdx, j+3, 64);
            float v0 = T[(long long)s0 * NH + lane];
            float v1 = T[(long long)s1 * NH + lane];
            float v2 = T[(long long)s2 * NH + lane];
            float v3 = T[(long long)s3 * NH + lane];
            acc += v0; acc += v1; acc += v2; acc += v3;
        }
        for (; j < m; ++j)
            acc += T[(long long)__shfl(sIdx, j, 64) * NH + lane];
    }
    O[(long long)node * NH + lane] = di * acc + b[lane];
}

// t2'[i] = dis[i] * (tanh(z1[i]) @ W2)  (64x2)
__global__ void __launch_bounds__(256) k_gemm2(
        const float* __restrict__ z1, const float* __restrict__ W2,
        const float* __restrict__ dis, float2* __restrict__ t2, int n) {
    __shared__ float Ws[NH * 2];
    if (threadIdx.x < NH * 2) Ws[threadIdx.x] = W2[threadIdx.x];
    __syncthreads();
    int i = blockIdx.x * 256 + threadIdx.x;
    if (i >= n) return;
    const float4* zr = (const float4*)(z1 + (long long)i * NH);
    float a0 = 0.0f, a1 = 0.0f;
    #pragma unroll
    for (int k4 = 0; k4 < NH / 4; ++k4) {
        float4 z = zr[k4];
        float t;
        t = tanhf(z.x); a0 += t * Ws[(k4*4+0)*2]; a1 += t * Ws[(k4*4+0)*2+1];
        t = tanhf(z.y); a0 += t * Ws[(k4*4+1)*2]; a1 += t * Ws[(k4*4+1)*2+1];
        t = tanhf(z.z); a0 += t * Ws[(k4*4+2)*2]; a1 += t * Ws[(k4*4+2)*2+1];
        t = tanhf(z.w); a0 += t * Ws[(k4*4+3)*2]; a1 += t * Ws[(k4*4+3)*2+1];
    }
    float di = dis[i];
    t2[i] = make_float2(a0 * di, a1 * di);
}

// agg2[i] = dis[i]*(t2[i] + sum t2[s]) + b2   (thread per node)
__global__ void __launch_bounds__(256) k_seg2(
        const float2* __restrict__ T2, const int* __restrict__ esrc,
        const int* __restrict__ start, const int* __restrict__ cnt,
        const float* __restrict__ dis, const float* __restrict__ b2,
        float2* __restrict__ O, int n) {
    int i = blockIdx.x * 256 + threadIdx.x;
    if (i >= n) return;
    float di = dis[i];
    int g = cnt[i], st = start[i];
    float2 self = T2[i];
    float a0 = self.x, a1 = self.y;
    for (int j = 0; j < g; ++j) {
        float2 v = T2[esrc[st + j]];
        a0 += v.x; a1 += v.y;
    }
    O[i] = make_float2(a0 * di + b2[0], a1 * di + b2[1]);
}

// emb = tanh(agg2) (agg2 aliases emb region); out = emb @ Wc + bc.
__global__ void __launch_bounds__(256) k_final(
        const float2* __restrict__ agg2, const float* __restrict__ Wc,
        const float* __restrict__ bc, float* __restrict__ out,
        float* __restrict__ emb, int n) {
    long long gid = (long long)blockIdx.x * 256 + threadIdx.x;
    int i = (int)(gid >> 4);
    int c = (int)(gid & 15);
    if (i >= n) return;
    float2 z = agg2[i];
    float e0 = tanhf(z.x), e1 = tanhf(z.y);
    out[(long long)i * 16 + c] = e0 * Wc[c] + e1 * Wc[16 + c] + bc[c];
    if (c == 0) emb[(long long)i * 2 + 0] = e0;
    if (c == 1) emb[(long long)i * 2 + 1] = e1;
}

extern "C" void kernel_launch(void* const* d_in, const int* in_sizes, int n_in,
                              void* d_out, int out_size, void* d_ws, size_t ws_size,
                              hipStream_t stream) {
    const float* x  = (const float*)d_in[0];
    const int*   ei = (const int*)  d_in[1];
    const float* W0 = (const float*)d_in[2];
    const float* b0 = (const float*)d_in[3];
    const float* W1 = (const float*)d_in[4];
    const float* b1 = (const float*)d_in[5];
    const float* W2 = (const float*)d_in[6];
    const float* b2 = (const float*)d_in[7];
    const float* Wc = (const float*)d_in[8];
    const float* bc = (const float*)d_in[9];

    int N = in_sizes[0] / NF;
    int E = in_sizes[1] / 2;

    float* out = (float*)d_out;                    // [N,16]
    float* emb = out + (long long)N * 16;          // [N,2]
    float2* t2   = (float2*)out;                   // scratch in out region
    float2* agg2 = (float2*)emb;                   // tanh'd in place by k_final

    // workspace: A[N*64] | B[N*64] | dis[N] | cnt[N] | start[N] | esrc[E] | fmt | gcount
    // rank[E] overlays A (A is dead until the GEMMs, which run after k_scatter).
    float* A      = (float*)d_ws;
    float* B      = A + (long long)N * NH;
    float* dis    = B + (long long)N * NH;
    int*   cnt    = (int*)(dis + N);
    int*   start  = cnt + N;
    int*   esrc   = start + N;
    int*   fmt    = esrc + E;
    int*   gcount = fmt + 1;
    int*   rank   = (int*)A;

    int nb_n   = (N + 255) / 256;
    int nb_e   = (E + 255) / 256;
    int nb_g   = (N + 63) / 64;
    int nb_s   = (N + 3) / 4;
    int nb_n16 = (int)(((long long)N * 16 + 255) / 256);

    // per-call bucketing (inputs restored before every call; same work each call)
    k_init    <<<nb_n, 256, 0, stream>>>(ei, fmt, cnt, gcount, N);
    k_cnt     <<<nb_e, 256, 0, stream>>>(ei, fmt, cnt, rank, E);
    k_scan    <<<nb_n, 256, 0, stream>>>(cnt, start, dis, gcount, N);
    k_scatter <<<nb_e, 256, 0, stream>>>(ei, fmt, start, rank, esrc, E);

    // layer 0 (no activation)
    k_gemm<NF><<<nb_g, 256, 0, stream>>>(x, W0, dis, A, N);
    k_seg     <<<nb_s, 256, 0, stream>>>(A, esrc, start, cnt, dis, b0, B, N);

    // layer 1 (tanh deferred into k_gemm2's read)
    k_gemm<NH><<<nb_g, 256, 0, stream>>>(B, W1, dis, A, N);
    k_seg     <<<nb_s, 256, 0, stream>>>(A, esrc, start, cnt, dis, b1, B, N);

    // layer 2 (2-wide) + head
    k_gemm2   <<<nb_n, 256, 0, stream>>>(B, W2, dis, t2, N);
    k_seg2    <<<nb_n, 256, 0, stream>>>(t2, esrc, start, cnt, dis, b2, agg2, N);
    k_final   <<<nb_n16, 256, 0, stream>>>(agg2, Wc, bc, out, emb, N);
}